// Round 1
// baseline (372.834 us; speedup 1.0000x reference)
//
#include <hip/hip_runtime.h>
#include <stdint.h>

typedef __bf16 bf16;
typedef __bf16 bf16x8 __attribute__((ext_vector_type(8)));
typedef float f32x4 __attribute__((ext_vector_type(4)));

#define MFMA16(a, b, c) __builtin_amdgcn_mfma_f32_16x16x32_bf16((a), (b), (c), 0, 0, 0)

// ---------------------------------------------------------------------------
// fp32 -> bf16 conversion for the 3 activations and 4 weight matrices.
// z selects the array; 8 elements per thread (2x float4 -> 1x bf16x8 store).
// ---------------------------------------------------------------------------
__global__ __launch_bounds__(256) void cvt_kernel(
    const float* __restrict__ q, const float* __restrict__ k, const float* __restrict__ v,
    const float* __restrict__ wq, const float* __restrict__ wk,
    const float* __restrict__ wv, const float* __restrict__ wo,
    bf16* __restrict__ qb, bf16* __restrict__ kb, bf16* __restrict__ vb,
    bf16* __restrict__ wqb, bf16* __restrict__ wkb, bf16* __restrict__ wvb,
    bf16* __restrict__ wob)
{
    int z = blockIdx.z;
    const float* src; bf16* dst; int n;
    switch (z) {
        case 0:  src = q;  dst = qb;  n = 4194304; break;
        case 1:  src = k;  dst = kb;  n = 4194304; break;
        case 2:  src = v;  dst = vb;  n = 4194304; break;
        case 3:  src = wq; dst = wqb; n = 1048576; break;
        case 4:  src = wk; dst = wkb; n = 1048576; break;
        case 5:  src = wv; dst = wvb; n = 1048576; break;
        default: src = wo; dst = wob; n = 1048576; break;
    }
    int i = (blockIdx.x * 256 + threadIdx.x) * 8;
    if (i >= n) return;
    float4 f0 = *(const float4*)(src + i);
    float4 f1 = *(const float4*)(src + i + 4);
    bf16x8 o;
    o[0] = (bf16)f0.x; o[1] = (bf16)f0.y; o[2] = (bf16)f0.z; o[3] = (bf16)f0.w;
    o[4] = (bf16)f1.x; o[5] = (bf16)f1.y; o[6] = (bf16)f1.z; o[7] = (bf16)f1.w;
    *(bf16x8*)(dst + i) = o;
}

// ---------------------------------------------------------------------------
// NT GEMM: C[m][n] = sum_k A[m][k] * B[n][k], M=4096, N=1024, K=1024.
// 128x128 block tile, 4 waves of 64x64, 16x16x32 bf16 MFMA, BK=32.
// LDS rows padded to 40 elems (80 B): frag ds_read_b128 banks = (row*20+quad*4)%32
// -> 2-way max (free per m136). OUTMODE 0: bf16 out, z in {0,1,2} selects Q/K/V.
// OUTMODE 1: fp32 out + bias.
// ---------------------------------------------------------------------------
template <int OUTMODE>
__global__ __launch_bounds__(256) void gemm_kernel(
    const bf16* __restrict__ A0, const bf16* __restrict__ A1, const bf16* __restrict__ A2,
    const bf16* __restrict__ B0, const bf16* __restrict__ B1, const bf16* __restrict__ B2,
    bf16* __restrict__ C0, bf16* __restrict__ C1, bf16* __restrict__ C2,
    const float* __restrict__ bias, float* __restrict__ outf)
{
    const int z = blockIdx.z;
    const bf16* A = (z == 0) ? A0 : (z == 1) ? A1 : A2;
    const bf16* B = (z == 0) ? B0 : (z == 1) ? B1 : B2;

    __shared__ bf16 At[128 * 40];
    __shared__ bf16 Bt[128 * 40];

    const int tid  = threadIdx.x;
    const int lane = tid & 63;
    const int wave = tid >> 6;
    const int quad = lane >> 4;
    const int l16  = lane & 15;
    const int wm = (wave >> 1) * 64;
    const int wn = (wave & 1) * 64;
    const int m0 = blockIdx.y * 128;
    const int n0 = blockIdx.x * 128;
    const int srow = tid >> 2;          // 0..63
    const int scol = (tid & 3) * 8;     // 0,8,16,24

    f32x4 acc[4][4] = {};

    const bf16* Ap = A + (m0 + srow) * 1024 + scol;
    const bf16* Bp = B + (n0 + srow) * 1024 + scol;

    for (int k0 = 0; k0 < 1024; k0 += 32) {
        uint4 a0 = *(const uint4*)(Ap + k0);
        uint4 a1 = *(const uint4*)(Ap + 64 * 1024 + k0);
        uint4 b0 = *(const uint4*)(Bp + k0);
        uint4 b1 = *(const uint4*)(Bp + 64 * 1024 + k0);
        __syncthreads();                 // previous iteration's frag reads done
        *(uint4*)(At + srow * 40 + scol)        = a0;
        *(uint4*)(At + (64 + srow) * 40 + scol) = a1;
        *(uint4*)(Bt + srow * 40 + scol)        = b0;
        *(uint4*)(Bt + (64 + srow) * 40 + scol) = b1;
        __syncthreads();

        bf16x8 af[4], bg[4];
#pragma unroll
        for (int i = 0; i < 4; ++i) {
            af[i] = *(const bf16x8*)(At + (wm + i * 16 + l16) * 40 + quad * 8);
            bg[i] = *(const bf16x8*)(Bt + (wn + i * 16 + l16) * 40 + quad * 8);
        }
#pragma unroll
        for (int i = 0; i < 4; ++i)
#pragma unroll
            for (int j = 0; j < 4; ++j)
                acc[i][j] = MFMA16(af[i], bg[j], acc[i][j]);
    }

    // C/D layout (m89-verified): col = lane&15, row = quad*4 + r
    if (OUTMODE == 0) {
        bf16* C = (z == 0) ? C0 : (z == 1) ? C1 : C2;
#pragma unroll
        for (int i = 0; i < 4; ++i)
#pragma unroll
            for (int j = 0; j < 4; ++j) {
                int row = m0 + wm + i * 16 + quad * 4;
                int col = n0 + wn + j * 16 + l16;
#pragma unroll
                for (int r = 0; r < 4; ++r)
                    C[(row + r) * 1024 + col] = (bf16)acc[i][j][r];
            }
    } else {
#pragma unroll
        for (int j = 0; j < 4; ++j) {
            int col = n0 + wn + j * 16 + l16;
            float bj = bias[col];
#pragma unroll
            for (int i = 0; i < 4; ++i) {
                int row = m0 + wm + i * 16 + quad * 4;
#pragma unroll
                for (int r = 0; r < 4; ++r)
                    outf[(row + r) * 1024 + col] = acc[i][j][r] + bj;
            }
        }
    }
}

// ---------------------------------------------------------------------------
// V [b*2048+s][1024] -> Vt [b][hd][s]  (64x64 LDS-tiled transpose)
// ---------------------------------------------------------------------------
__global__ __launch_bounds__(256) void transpose_kernel(const bf16* __restrict__ V,
                                                        bf16* __restrict__ Vt)
{
    __shared__ bf16 t[64][72];
    const int tid = threadIdx.x;
    const int b  = blockIdx.z;
    const int s0 = blockIdx.x * 64;
    const int d0 = blockIdx.y * 64;
#pragma unroll
    for (int c = 0; c < 2; ++c) {
        int qq = c * 256 + tid;
        int row = qq >> 3, col = (qq & 7) * 8;
        *(uint4*)(&t[row][col]) =
            *(const uint4*)(V + (size_t)(b * 2048 + s0 + row) * 1024 + d0 + col);
    }
    __syncthreads();
#pragma unroll
    for (int c = 0; c < 2; ++c) {
        int qq = c * 256 + tid;
        int drow = qq >> 3, scol = (qq & 7) * 8;
        bf16x8 o;
#pragma unroll
        for (int j = 0; j < 8; ++j) o[j] = t[scol + j][drow];
        *(bf16x8*)(Vt + (size_t)(b * 1024 + d0 + drow) * 2048 + s0 + scol) = o;
    }
}

// ---------------------------------------------------------------------------
// Flash attention: one block = 64 q-rows of one (b,h); 4 waves x 16 q-rows.
// k-tile = 32. K tile staged [32 key][72 pad] (B-frag = contiguous d), V tile
// staged from pre-transposed Vt as [64 d][40 pad] (B-frag = contiguous keys).
// Online softmax fp32 in C-layout (row = quad*4+r, col = lane&15); P goes
// C-layout -> LDS -> A-layout (A[m=lane&15][k=quad*8+j], per m120).
// energy scale = 1/sqrt(EMBED_DIM) = 1/32 (faithful to source).
// ---------------------------------------------------------------------------
__global__ __launch_bounds__(256) void flash_kernel(
    const bf16* __restrict__ Q, const bf16* __restrict__ K, const bf16* __restrict__ Vt,
    const int* __restrict__ mask, bf16* __restrict__ O)
{
    __shared__ bf16 Kl[32 * 72];
    __shared__ bf16 Vl[64 * 40];
    __shared__ bf16 Pl[4][16 * 40];

    const int tid  = threadIdx.x;
    const int lane = tid & 63;
    const int wave = tid >> 6;
    const int quad = lane >> 4;
    const int l16  = lane & 15;
    const int b  = blockIdx.z;
    const int h  = blockIdx.y;
    const int q0 = blockIdx.x * 64;

    const bf16* Qp = Q + (size_t)(b * 2048 + q0 + wave * 16 + l16) * 1024 + h * 64;
    bf16x8 qf0 = *(const bf16x8*)(Qp + quad * 8);        // A[m=l16][k=quad*8+j], d 0..31
    bf16x8 qf1 = *(const bf16x8*)(Qp + 32 + quad * 8);   // d 32..63

    f32x4 acc[4] = {};
    float m_i[4], l_i[4];
#pragma unroll
    for (int r = 0; r < 4; ++r) { m_i[r] = -3.0e38f; l_i[r] = 0.0f; }

    const int krow = tid >> 3, kcol = (tid & 7) * 8;   // 32 keys x 8 d-chunks
    const int vrow = tid >> 2, vcol = (tid & 3) * 8;   // 64 d    x 4 s-chunks
    const bf16* Kp = K + (size_t)(b * 2048 + krow) * 1024 + h * 64 + kcol;
    const bf16* Vp = Vt + (size_t)((b * 16 + h) * 64 + vrow) * 2048 + vcol;
    const int mrow = (q0 + wave * 16 + quad * 4) * 2048;

    for (int kt0 = 0; kt0 < 2048; kt0 += 32) {
        uint4 kv = *(const uint4*)(Kp + (size_t)kt0 * 1024);
        uint4 vv = *(const uint4*)(Vp + kt0);
        __syncthreads();                 // all waves done reading prev K/V tiles
        *(uint4*)(Kl + krow * 72 + kcol) = kv;
        *(uint4*)(Vl + vrow * 40 + vcol) = vv;
        __syncthreads();

        // S = Q K^T (two 16-key chunks, each accumulating d 0..63)
        f32x4 s0 = {}, s1 = {};
        {
            bf16x8 k00 = *(const bf16x8*)(Kl + l16 * 72 + quad * 8);
            bf16x8 k01 = *(const bf16x8*)(Kl + l16 * 72 + 32 + quad * 8);
            s0 = MFMA16(qf0, k00, s0);
            s0 = MFMA16(qf1, k01, s0);
            bf16x8 k10 = *(const bf16x8*)(Kl + (16 + l16) * 72 + quad * 8);
            bf16x8 k11 = *(const bf16x8*)(Kl + (16 + l16) * 72 + 32 + quad * 8);
            s1 = MFMA16(qf0, k10, s1);
            s1 = MFMA16(qf1, k11, s1);
        }

        float p0[4], p1[4], mt[4];
#pragma unroll
        for (int r = 0; r < 4; ++r) {
            float a = s0[r] * 0.03125f;          // /sqrt(1024)
            float c = s1[r] * 0.03125f;
            int base = mrow + r * 2048 + kt0;
            if (mask[base + l16] == 0)      a = -1e20f;
            if (mask[base + 16 + l16] == 0) c = -1e20f;
            p0[r] = a; p1[r] = c;
            mt[r] = fmaxf(a, c);
        }
#pragma unroll
        for (int off = 1; off < 16; off <<= 1)
#pragma unroll
            for (int r = 0; r < 4; ++r)
                mt[r] = fmaxf(mt[r], __shfl_xor(mt[r], off));

        float alpha[4], rs[4];
#pragma unroll
        for (int r = 0; r < 4; ++r) {
            float mn = fmaxf(m_i[r], mt[r]);
            alpha[r] = __expf(m_i[r] - mn);
            m_i[r] = mn;
            p0[r] = __expf(p0[r] - mn);
            p1[r] = __expf(p1[r] - mn);
            rs[r] = p0[r] + p1[r];
        }
#pragma unroll
        for (int off = 1; off < 16; off <<= 1)
#pragma unroll
            for (int r = 0; r < 4; ++r)
                rs[r] += __shfl_xor(rs[r], off);
#pragma unroll
        for (int r = 0; r < 4; ++r)
            l_i[r] = l_i[r] * alpha[r] + rs[r];
#pragma unroll
        for (int nc = 0; nc < 4; ++nc)
#pragma unroll
            for (int r = 0; r < 4; ++r)
                acc[nc][r] *= alpha[r];

        // P: C-layout -> LDS -> A-layout
        bf16* Pw = Pl[wave];
#pragma unroll
        for (int r = 0; r < 4; ++r) {
            Pw[(quad * 4 + r) * 40 + l16]      = (bf16)p0[r];
            Pw[(quad * 4 + r) * 40 + 16 + l16] = (bf16)p1[r];
        }
        __syncthreads();                 // also orders wave-local P write->read
        bf16x8 pa = *(const bf16x8*)(Pl[wave] + l16 * 40 + quad * 8);
#pragma unroll
        for (int nc = 0; nc < 4; ++nc) {
            bf16x8 vf = *(const bf16x8*)(Vl + (nc * 16 + l16) * 40 + quad * 8);
            acc[nc] = MFMA16(pa, vf, acc[nc]);
        }
    }

    const int orow = b * 2048 + q0 + wave * 16 + quad * 4;
#pragma unroll
    for (int r = 0; r < 4; ++r) {
        float inv = 1.0f / l_i[r];
#pragma unroll
        for (int nc = 0; nc < 4; ++nc)
            O[(size_t)(orow + r) * 1024 + h * 64 + nc * 16 + l16] =
                (bf16)(acc[nc][r] * inv);
    }
}

// ---------------------------------------------------------------------------
extern "C" void kernel_launch(void* const* d_in, const int* in_sizes, int n_in,
                              void* d_out, int out_size, void* d_ws, size_t ws_size,
                              hipStream_t stream)
{
    const float* q  = (const float*)d_in[0];
    const float* k  = (const float*)d_in[1];
    const float* v  = (const float*)d_in[2];
    const int* mask = (const int*)d_in[3];
    const float* wq = (const float*)d_in[4];
    const float* wk = (const float*)d_in[5];
    const float* wv = (const float*)d_in[6];
    const float* wo = (const float*)d_in[7];
    const float* bo = (const float*)d_in[8];
    float* out = (float*)d_out;

    char* p = (char*)d_ws;
    auto alloc = [&](size_t bytes) {
        char* r = p;
        p += (bytes + 255) & ~(size_t)255;
        return r;
    };
    const size_t SB = (size_t)4096 * 1024 * 2;  // one [4096][1024] bf16 tensor
    const size_t WB = (size_t)1024 * 1024 * 2;  // one [1024][1024] bf16 weight
    bf16* qb  = (bf16*)alloc(SB);
    bf16* kb  = (bf16*)alloc(SB);
    bf16* vb  = (bf16*)alloc(SB);
    bf16* wqb = (bf16*)alloc(WB);
    bf16* wkb = (bf16*)alloc(WB);
    bf16* wvb = (bf16*)alloc(WB);
    bf16* wob = (bf16*)alloc(WB);
    bf16* Qp  = (bf16*)alloc(SB);
    bf16* Kp  = (bf16*)alloc(SB);
    bf16* Vp  = (bf16*)alloc(SB);
    bf16* Vtp = (bf16*)alloc(SB);
    bf16* Ob  = (bf16*)alloc(SB);

    cvt_kernel<<<dim3(2048, 1, 7), 256, 0, stream>>>(
        q, k, v, wq, wk, wv, wo, qb, kb, vb, wqb, wkb, wvb, wob);

    gemm_kernel<0><<<dim3(8, 32, 3), 256, 0, stream>>>(
        qb, kb, vb, wqb, wkb, wvb, Qp, Kp, Vp, nullptr, nullptr);

    transpose_kernel<<<dim3(32, 16, 2), 256, 0, stream>>>(Vp, Vtp);

    flash_kernel<<<dim3(32, 16, 2), 256, 0, stream>>>(Qp, Kp, Vtp, mask, Ob);

    gemm_kernel<1><<<dim3(8, 32, 1), 256, 0, stream>>>(
        Ob, nullptr, nullptr, wob, nullptr, nullptr,
        nullptr, nullptr, nullptr, bo, out);
}

// Round 2
// 320.781 us; speedup vs baseline: 1.1623x; 1.1623x over previous
//
#include <hip/hip_runtime.h>
#include <stdint.h>

typedef __bf16 bf16;
typedef __bf16 bf16x8 __attribute__((ext_vector_type(8)));
typedef float f32x4 __attribute__((ext_vector_type(4)));

#define MFMA16(a, b, c) __builtin_amdgcn_mfma_f32_16x16x32_bf16((a), (b), (c), 0, 0, 0)

// Load 8 contiguous elements as bf16x8; F32=1 reads fp32 and converts.
template <int F32>
__device__ __forceinline__ bf16x8 ld8(const char* p) {
    if constexpr (F32) {
        float4 f0 = *(const float4*)p;
        float4 f1 = *(const float4*)(p + 16);
        bf16x8 o;
        o[0] = (bf16)f0.x; o[1] = (bf16)f0.y; o[2] = (bf16)f0.z; o[3] = (bf16)f0.w;
        o[4] = (bf16)f1.x; o[5] = (bf16)f1.y; o[6] = (bf16)f1.z; o[7] = (bf16)f1.w;
        return o;
    } else {
        return *(const bf16x8*)p;
    }
}

// ---------------------------------------------------------------------------
// mask [2048][2048] int32 -> maskb [2048][32] uint64 (bit k of word w =
// mask[row][w*64+k] != 0). One wave per output word via __ballot.
// ---------------------------------------------------------------------------
__global__ __launch_bounds__(256) void maskpack_kernel(
    const int* __restrict__ mask, unsigned long long* __restrict__ maskb)
{
    int gid  = blockIdx.x * 256 + threadIdx.x;
    int word = gid >> 6;          // 0..65535
    int lane = gid & 63;
    int row = word >> 5, wc = word & 31;
    int mv = mask[row * 2048 + wc * 64 + lane];
    unsigned long long bits = __ballot(mv != 0);
    if (lane == 0) maskb[word] = bits;
}

// ---------------------------------------------------------------------------
// NT GEMM: C[m][n] = sum_k A[m][k]*B[n][k], K=1024, N=1024, M=4096.
// MT x 128 block tile (MT=128: 4 waves 64x64; MT=64: 4 waves 32x64), BK=32.
// fp32 inputs converted to bf16 during staging (AF32/BF32). LDS rows padded
// to 40 elems -> frag ds_read_b128 is 2-way max (free per m136).
// OUTMODE 0: bf16 out, z selects {Q,K,V}. OUTMODE 1: fp32 out + bias.
// ---------------------------------------------------------------------------
template <int OUTMODE, int AF32, int BF32, int MT>
__global__ __launch_bounds__(256) void gemm_kernel(
    const void* __restrict__ A0, const void* __restrict__ A1, const void* __restrict__ A2,
    const void* __restrict__ B0, const void* __restrict__ B1, const void* __restrict__ B2,
    bf16* __restrict__ C0, bf16* __restrict__ C1, bf16* __restrict__ C2,
    const float* __restrict__ bias, float* __restrict__ outf)
{
    constexpr int ASZ = AF32 ? 4 : 2;
    constexpr int BSZ = BF32 ? 4 : 2;
    constexpr int MI  = (MT == 128) ? 4 : 2;   // m-frags per wave

    const int z = blockIdx.z;
    const char* A = (const char*)((z == 0) ? A0 : (z == 1) ? A1 : A2);
    const char* B = (const char*)((z == 0) ? B0 : (z == 1) ? B1 : B2);

    __shared__ bf16 At[MT * 40];
    __shared__ bf16 Bt[128 * 40];

    const int tid  = threadIdx.x;
    const int lane = tid & 63;
    const int wave = tid >> 6;
    const int quad = lane >> 4;
    const int l16  = lane & 15;
    const int wm = (wave >> 1) * (MT / 2);
    const int wn = (wave & 1) * 64;
    const int m0 = blockIdx.y * MT;
    const int n0 = blockIdx.x * 128;
    const int srow = tid >> 2;          // 0..63
    const int scol = (tid & 3) * 8;     // 0,8,16,24

    f32x4 acc[MI][4] = {};

    const char* Ap = A + ((size_t)(m0 + srow) * 1024 + scol) * ASZ;
    const char* Bp = B + ((size_t)(n0 + srow) * 1024 + scol) * BSZ;

    for (int k0 = 0; k0 < 1024; k0 += 32) {
        bf16x8 a0 = ld8<AF32>(Ap + k0 * ASZ);
        bf16x8 a1 = {};
        if constexpr (MT == 128) a1 = ld8<AF32>(Ap + (64 * 1024 + k0) * ASZ);
        bf16x8 b0 = ld8<BF32>(Bp + k0 * BSZ);
        bf16x8 b1 = ld8<BF32>(Bp + (64 * 1024 + k0) * BSZ);
        __syncthreads();                 // previous iteration's frag reads done
        *(bf16x8*)(At + srow * 40 + scol) = a0;
        if constexpr (MT == 128) *(bf16x8*)(At + (64 + srow) * 40 + scol) = a1;
        *(bf16x8*)(Bt + srow * 40 + scol) = b0;
        *(bf16x8*)(Bt + (64 + srow) * 40 + scol) = b1;
        __syncthreads();

        bf16x8 af[MI], bg[4];
#pragma unroll
        for (int i = 0; i < MI; ++i)
            af[i] = *(const bf16x8*)(At + (wm + i * 16 + l16) * 40 + quad * 8);
#pragma unroll
        for (int j = 0; j < 4; ++j)
            bg[j] = *(const bf16x8*)(Bt + (wn + j * 16 + l16) * 40 + quad * 8);
#pragma unroll
        for (int i = 0; i < MI; ++i)
#pragma unroll
            for (int j = 0; j < 4; ++j)
                acc[i][j] = MFMA16(af[i], bg[j], acc[i][j]);
    }

    // C/D layout (m89-verified): col = lane&15, row = quad*4 + r
    if constexpr (OUTMODE == 0) {
        bf16* C = (z == 0) ? C0 : (z == 1) ? C1 : C2;
#pragma unroll
        for (int i = 0; i < MI; ++i)
#pragma unroll
            for (int j = 0; j < 4; ++j) {
                int row = m0 + wm + i * 16 + quad * 4;
                int col = n0 + wn + j * 16 + l16;
#pragma unroll
                for (int r = 0; r < 4; ++r)
                    C[(row + r) * 1024 + col] = (bf16)acc[i][j][r];
            }
    } else {
#pragma unroll
        for (int j = 0; j < 4; ++j) {
            int col = n0 + wn + j * 16 + l16;
            float bj = bias[col];
#pragma unroll
            for (int i = 0; i < MI; ++i) {
                int row = m0 + wm + i * 16 + quad * 4;
#pragma unroll
                for (int r = 0; r < 4; ++r)
                    outf[(row + r) * 1024 + col] = acc[i][j][r] + bj;
            }
        }
    }
}

// ---------------------------------------------------------------------------
// V [b*2048+s][1024] -> Vt [b][h*64+d][s]  (64x64 LDS-tiled transpose)
// ---------------------------------------------------------------------------
__global__ __launch_bounds__(256) void transpose_kernel(const bf16* __restrict__ V,
                                                        bf16* __restrict__ Vt)
{
    __shared__ bf16 t[64][72];
    const int tid = threadIdx.x;
    const int b  = blockIdx.z;
    const int s0 = blockIdx.x * 64;
    const int d0 = blockIdx.y * 64;
#pragma unroll
    for (int c = 0; c < 2; ++c) {
        int qq = c * 256 + tid;
        int row = qq >> 3, col = (qq & 7) * 8;
        *(uint4*)(&t[row][col]) =
            *(const uint4*)(V + (size_t)(b * 2048 + s0 + row) * 1024 + d0 + col);
    }
    __syncthreads();
#pragma unroll
    for (int c = 0; c < 2; ++c) {
        int qq = c * 256 + tid;
        int drow = qq >> 3, scol = (qq & 7) * 8;
        bf16x8 o;
#pragma unroll
        for (int j = 0; j < 8; ++j) o[j] = t[scol + j][drow];
        *(bf16x8*)(Vt + (size_t)(b * 1024 + d0 + drow) * 2048 + s0 + scol) = o;
    }
}

// ---------------------------------------------------------------------------
// Flash attention: block = 64 q-rows of one (b,h); 4 waves x 16 q-rows.
// k-tile = 64 (4 chunks of 16). Mask via bit-packed uint64 words (uniform
// loads). Row-sum l_i via an extra PV MFMA against a ones B-frag: lacc lives
// in C-layout, rescaled by the same alpha as acc -> no sum shuffle tree and
// no end-of-loop broadcast (all 16 n-cols identical). P C->A layout transform
// through wave-private LDS (no barrier needed: same-wave ds ordering).
// energy scale = 1/sqrt(EMBED_DIM) = 1/32 (faithful to source).
// ---------------------------------------------------------------------------
__global__ __launch_bounds__(256) void flash_kernel(
    const bf16* __restrict__ Q, const bf16* __restrict__ K, const bf16* __restrict__ Vt,
    const unsigned long long* __restrict__ maskb, bf16* __restrict__ O)
{
    __shared__ bf16 Kl[64 * 72];
    __shared__ bf16 Vl[64 * 72];
    __shared__ bf16 Pl[4][16 * 72];

    const int tid  = threadIdx.x;
    const int lane = tid & 63;
    const int wave = tid >> 6;
    const int quad = lane >> 4;
    const int l16  = lane & 15;
    const int b  = blockIdx.z;
    const int h  = blockIdx.y;
    const int q0 = blockIdx.x * 64;

    // Q A-frags: A[m=l16][k=quad*8+j]
    const bf16* Qp = Q + (size_t)(b * 2048 + q0 + wave * 16 + l16) * 1024 + h * 64;
    bf16x8 qf0 = *(const bf16x8*)(Qp + quad * 8);        // d 0..31
    bf16x8 qf1 = *(const bf16x8*)(Qp + 32 + quad * 8);   // d 32..63

    bf16x8 ones;
#pragma unroll
    for (int j = 0; j < 8; ++j) ones[j] = (bf16)1.0f;

    f32x4 acc[4] = {};
    f32x4 lacc = {};
    float m_i[4];
#pragma unroll
    for (int r = 0; r < 4; ++r) m_i[r] = -3.0e38f;

    const int srow = tid >> 3;          // 0..31
    const int scol = (tid & 7) * 8;     // 0..56
    const bf16* Kp = K + (size_t)(b * 2048 + srow) * 1024 + h * 64 + scol;
    const bf16* Vp = Vt + (size_t)((b * 16 + h) * 64 + srow) * 2048 + scol;
    const int mbase = (q0 + wave * 16 + quad * 4) * 32;   // 32 uint64 words/row

    for (int kt = 0; kt < 2048; kt += 64) {
        uint4 k0v = *(const uint4*)(Kp + (size_t)kt * 1024);
        uint4 k1v = *(const uint4*)(Kp + (size_t)(kt + 32) * 1024);
        uint4 v0v = *(const uint4*)(Vp + kt);
        uint4 v1v = *(const uint4*)(Vp + 32 * 2048 + kt);
        unsigned long long mw[4];
#pragma unroll
        for (int r = 0; r < 4; ++r) mw[r] = maskb[mbase + r * 32 + (kt >> 6)];

        __syncthreads();                 // all waves done reading prev K/V tiles
        *(uint4*)(Kl + srow * 72 + scol)        = k0v;
        *(uint4*)(Kl + (srow + 32) * 72 + scol) = k1v;
        *(uint4*)(Vl + srow * 72 + scol)        = v0v;
        *(uint4*)(Vl + (srow + 32) * 72 + scol) = v1v;
        __syncthreads();

        // S = Q K^T: 4 chunks of 16 keys, d accumulated over 0..63
        f32x4 s[4];
#pragma unroll
        for (int kc = 0; kc < 4; ++kc) {
            bf16x8 ka = *(const bf16x8*)(Kl + (kc * 16 + l16) * 72 + quad * 8);
            bf16x8 kb = *(const bf16x8*)(Kl + (kc * 16 + l16) * 72 + 32 + quad * 8);
            f32x4 t = {};
            t = MFMA16(qf0, ka, t);
            t = MFMA16(qf1, kb, t);
            s[kc] = t;
        }

        // scale + mask + per-thread max
        float sc[4][4];
        float mt[4];
#pragma unroll
        for (int r = 0; r < 4; ++r) mt[r] = -3.0e38f;
#pragma unroll
        for (int kc = 0; kc < 4; ++kc)
#pragma unroll
            for (int r = 0; r < 4; ++r) {
                float a = s[kc][r] * 0.03125f;        // /sqrt(1024)
                bool keep = (mw[r] >> (kc * 16 + l16)) & 1ULL;
                a = keep ? a : -1.0e20f;
                sc[kc][r] = a;
                mt[r] = fmaxf(mt[r], a);
            }
        // max across the 16 lanes of each row
#pragma unroll
        for (int off = 1; off < 16; off <<= 1)
#pragma unroll
            for (int r = 0; r < 4; ++r)
                mt[r] = fmaxf(mt[r], __shfl_xor(mt[r], off));

        float alpha[4];
#pragma unroll
        for (int r = 0; r < 4; ++r) {
            float mn = fmaxf(m_i[r], mt[r]);
            alpha[r] = __expf(m_i[r] - mn);
            m_i[r] = mn;
        }
#pragma unroll
        for (int kc = 0; kc < 4; ++kc)
#pragma unroll
            for (int r = 0; r < 4; ++r)
                sc[kc][r] = __expf(sc[kc][r] - m_i[r]);
#pragma unroll
        for (int nc = 0; nc < 4; ++nc)
#pragma unroll
            for (int r = 0; r < 4; ++r)
                acc[nc][r] *= alpha[r];
#pragma unroll
        for (int r = 0; r < 4; ++r)
            lacc[r] *= alpha[r];

        // P: C-layout -> wave-private LDS -> A-layout (no barrier needed)
        bf16* Pw = Pl[wave];
#pragma unroll
        for (int r = 0; r < 4; ++r)
#pragma unroll
            for (int kc = 0; kc < 4; ++kc)
                Pw[(quad * 4 + r) * 72 + kc * 16 + l16] = (bf16)sc[kc][r];

        bf16x8 pa0 = *(const bf16x8*)(Pw + l16 * 72 + quad * 8);        // keys 0..31
        bf16x8 pa1 = *(const bf16x8*)(Pw + l16 * 72 + 32 + quad * 8);   // keys 32..63

#pragma unroll
        for (int nc = 0; nc < 4; ++nc) {
            bf16x8 v0 = *(const bf16x8*)(Vl + (nc * 16 + l16) * 72 + quad * 8);
            bf16x8 v1 = *(const bf16x8*)(Vl + (nc * 16 + l16) * 72 + 32 + quad * 8);
            acc[nc] = MFMA16(pa0, v0, acc[nc]);
            acc[nc] = MFMA16(pa1, v1, acc[nc]);
        }
        lacc = MFMA16(pa0, ones, lacc);   // row-sum: every n-col identical
        lacc = MFMA16(pa1, ones, lacc);
    }

    const int orow = b * 2048 + q0 + wave * 16 + quad * 4;
#pragma unroll
    for (int r = 0; r < 4; ++r) {
        float inv = 1.0f / lacc[r];
#pragma unroll
        for (int nc = 0; nc < 4; ++nc)
            O[(size_t)(orow + r) * 1024 + h * 64 + nc * 16 + l16] =
                (bf16)(acc[nc][r] * inv);
    }
}

// ---------------------------------------------------------------------------
extern "C" void kernel_launch(void* const* d_in, const int* in_sizes, int n_in,
                              void* d_out, int out_size, void* d_ws, size_t ws_size,
                              hipStream_t stream)
{
    const float* q  = (const float*)d_in[0];
    const float* k  = (const float*)d_in[1];
    const float* v  = (const float*)d_in[2];
    const int* mask = (const int*)d_in[3];
    const float* wq = (const float*)d_in[4];
    const float* wk = (const float*)d_in[5];
    const float* wv = (const float*)d_in[6];
    const float* wo = (const float*)d_in[7];
    const float* bo = (const float*)d_in[8];
    float* out = (float*)d_out;

    char* p = (char*)d_ws;
    auto alloc = [&](size_t bytes) {
        char* r = p;
        p += (bytes + 255) & ~(size_t)255;
        return r;
    };
    const size_t SB = (size_t)4096 * 1024 * 2;  // one [4096][1024] bf16 tensor
    bf16* Qp  = (bf16*)alloc(SB);
    bf16* Kp  = (bf16*)alloc(SB);
    bf16* Vp  = (bf16*)alloc(SB);
    bf16* Vtp = (bf16*)alloc(SB);
    bf16* Ob  = (bf16*)alloc(SB);
    unsigned long long* maskb = (unsigned long long*)alloc(2048 * 32 * 8);

    maskpack_kernel<<<dim3(16384), 256, 0, stream>>>(mask, maskb);

    gemm_kernel<0, 1, 1, 128><<<dim3(8, 32, 3), 256, 0, stream>>>(
        q, k, v, wq, wk, wv, Qp, Kp, Vp, nullptr, nullptr);

    transpose_kernel<<<dim3(32, 16, 2), 256, 0, stream>>>(Vp, Vtp);

    flash_kernel<<<dim3(32, 16, 2), 256, 0, stream>>>(Qp, Kp, Vtp, maskb, Ob);

    gemm_kernel<1, 0, 1, 64><<<dim3(8, 64, 1), 256, 0, stream>>>(
        Ob, nullptr, nullptr, wo, nullptr, nullptr,
        nullptr, nullptr, nullptr, bo, out);
}